// Round 5
// baseline (169.727 us; speedup 1.0000x reference)
//
#include <hip/hip_runtime.h>
#include <hip/hip_bf16.h>

#define B_ 2
#define S_ 2048
#define D_ 1024
#define H_ 16
#define HD_ 64
#define KDIM 1024

typedef __attribute__((ext_vector_type(8))) short s16x8;
typedef __attribute__((ext_vector_type(8))) __bf16 bf16x8;
typedef __attribute__((ext_vector_type(4))) float f32x4;
typedef __attribute__((ext_vector_type(16))) float f32x16;
typedef __attribute__((ext_vector_type(4))) unsigned short u16x4;

__device__ __forceinline__ unsigned short f2bf(float f) {
  union { __bf16 b; unsigned short u; } v;
  v.b = (__bf16)f;
  return v.u;
}

__device__ __forceinline__ unsigned pk2(float lo, float hi) {
  union { unsigned short s[2]; unsigned u; } r;
  r.s[0] = f2bf(lo); r.s[1] = f2bf(hi);
  return r.u;
}

// permlane32_swap(a, b): HW swaps a[32+j] <-> b[j].
//   ret0 = new a = [a(0..31) | b-values-from-partner-low]
//   ret1 = new b = [a-values-from-partner-high | b(32..63)]
__device__ __forceinline__ void plswap2(unsigned& a_out, unsigned& b_out,
                                        unsigned a, unsigned b) {
  auto rr = __builtin_amdgcn_permlane32_swap(a, b, false, false);
  unsigned out[2];
  __builtin_memcpy(out, &rr, 8);
  a_out = out[0];
  b_out = out[1];
}

#define MFMA16(a, b, c) __builtin_amdgcn_mfma_f32_16x16x32_bf16((a), (b), (c), 0, 0, 0)
#define MFMA32(a, b, c) __builtin_amdgcn_mfma_f32_32x32x16_bf16((a), (b), (c), 0, 0, 0)

__device__ __forceinline__ void gll16(const void* g, void* l) {
  __builtin_amdgcn_global_load_lds(
      (const __attribute__((address_space(1))) void*)g,
      (__attribute__((address_space(3))) void*)l, 16, 0, 0);
}

// ---------------- X fp32 -> bf16
__global__ __launch_bounds__(256) void x2bf(const float* __restrict__ X,
                                            unsigned short* __restrict__ Xb) {
  const int i = (blockIdx.x * 256 + threadIdx.x) * 8;
  const float4 a = *reinterpret_cast<const float4*>(X + i);
  const float4 b = *reinterpret_cast<const float4*>(X + i + 4);
  u16x4 lo = {f2bf(a.x), f2bf(a.y), f2bf(a.z), f2bf(a.w)};
  u16x4 hi = {f2bf(b.x), f2bf(b.y), f2bf(b.z), f2bf(b.w)};
  *reinterpret_cast<u16x4*>(Xb + i) = lo;
  *reinterpret_cast<u16x4*>(Xb + i + 4) = hi;
}

// ---------------- transpose+convert: W[1024][N] fp32 -> Wt[N][1024] bf16
__global__ __launch_bounds__(256) void transpose_w(const float* __restrict__ W,
                                                   unsigned short* __restrict__ Wt,
                                                   int N) {
  __shared__ float T[64][65];
  const int k0 = blockIdx.y * 64, n0 = blockIdx.x * 64;
  const int t = threadIdx.x;
  const int lr = t >> 4, lc = (t & 15) * 4;
#pragma unroll
  for (int p = 0; p < 4; ++p) {
    const int r = lr + p * 16;
    const float4 v = *reinterpret_cast<const float4*>(W + (size_t)(k0 + r) * N + n0 + lc);
    T[r][lc + 0] = v.x; T[r][lc + 1] = v.y; T[r][lc + 2] = v.z; T[r][lc + 3] = v.w;
  }
  __syncthreads();
  const int wn = t >> 4, wk = (t & 15) * 4;
#pragma unroll
  for (int p = 0; p < 4; ++p) {
    const int n = wn + p * 16;
    u16x4 o = {f2bf(T[wk + 0][n]), f2bf(T[wk + 1][n]), f2bf(T[wk + 2][n]), f2bf(T[wk + 3][n])};
    *reinterpret_cast<u16x4*>(Wt + (size_t)(n0 + n) * 1024 + k0 + wk) = o;
  }
}

// ---------------- QKV projection -> Q/K [b,h,s,hd], V directly transposed [b,h,hd,s]
__global__ __launch_bounds__(256) void gemm_qkv(
    const unsigned short* __restrict__ Xb, const unsigned short* __restrict__ WT,
    const float* __restrict__ bias,
    unsigned short* __restrict__ Qo, unsigned short* __restrict__ Ko,
    unsigned short* __restrict__ Vt) {
  __shared__ __align__(16) unsigned short As[128][72];
  __shared__ __align__(16) unsigned short Bs[128][72];
  const int m0 = blockIdx.y * 128, n0 = blockIdx.x * 128;
  const int t = threadIdx.x;
  const int lane = t & 63, wid = t >> 6;
  const int wr = wid >> 1, wc = wid & 1;
  const int l15 = lane & 15, l16 = lane >> 4;
  f32x4 acc[4][4] = {};
  const int col8 = (t & 7) * 8, row8 = t >> 3;
  for (int k0 = 0; k0 < KDIM; k0 += 64) {
#pragma unroll
    for (int u = 0; u < 4; ++u) {
      const int row = row8 + u * 32;
      *reinterpret_cast<s16x8*>(&As[row][col8]) =
          *reinterpret_cast<const s16x8*>(Xb + (size_t)(m0 + row) * KDIM + k0 + col8);
    }
#pragma unroll
    for (int u = 0; u < 4; ++u) {
      const int row = row8 + u * 32;
      *reinterpret_cast<s16x8*>(&Bs[row][col8]) =
          *reinterpret_cast<const s16x8*>(WT + (size_t)(n0 + row) * KDIM + k0 + col8);
    }
    __syncthreads();
#pragma unroll
    for (int ks = 0; ks < 2; ++ks) {
      bf16x8 af[4], bfr[4];
#pragma unroll
      for (int m = 0; m < 4; ++m)
        af[m] = *reinterpret_cast<const bf16x8*>(&As[wr * 64 + m * 16 + l15][ks * 32 + l16 * 8]);
#pragma unroll
      for (int n = 0; n < 4; ++n)
        bfr[n] = *reinterpret_cast<const bf16x8*>(&Bs[wc * 64 + n * 16 + l15][ks * 32 + l16 * 8]);
#pragma unroll
      for (int m = 0; m < 4; ++m)
#pragma unroll
        for (int n = 0; n < 4; ++n)
          acc[m][n] = MFMA16(af[m], bfr[n], acc[m][n]);
    }
    __syncthreads();
  }
#pragma unroll
  for (int n = 0; n < 4; ++n) {
    const int col = n0 + wc * 64 + n * 16 + l15;
    const float bv = bias[col];
    const int which = col >> 10;
    const int dcol = col & 1023;
    const int hh = dcol >> 6, hd = dcol & 63;
#pragma unroll
    for (int m = 0; m < 4; ++m) {
#pragma unroll
      for (int j = 0; j < 4; ++j) {
        const int row = m0 + wr * 64 + m * 16 + l16 * 4 + j;
        const int bb = row >> 11, s = row & 2047;
        const unsigned short val = f2bf(acc[m][n][j] + bv);
        if (which == 0)
          Qo[(((size_t)bb * H_ + hh) * S_ + s) * HD_ + hd] = val;
        else if (which == 1)
          Ko[(((size_t)bb * H_ + hh) * S_ + s) * HD_ + hd] = val;
        else
          Vt[(((size_t)bb * H_ + hh) * HD_ + hd) * S_ + s] = val;
      }
    }
  }
}

// ---------------- Flash attention: swapped 32x32 MFMA, in-register softmax.
// 512 blocks (4 waves x 32 q-rows = 128 q-rows each), heavy-first, XCD-mapped.
__global__ __launch_bounds__(256, 4) void attn(
    const unsigned short* __restrict__ Qb, const unsigned short* __restrict__ Kb,
    const unsigned short* __restrict__ Vt, unsigned short* __restrict__ Cxt) {
  __shared__ __align__(16) unsigned short Kl[2][4096];  // [kv 64][hd 64] swizzled
  __shared__ __align__(16) unsigned short Vl[2][4096];  // [hd 64][kv 64] swizzled
  const int bi = blockIdx.x;
  const int xcd = bi & 7, slot = bi >> 3;
  const int bh = xcd * 4 + (slot & 3);    // 4 heads per XCD -> K/V L2-resident
  const int qt = 15 - (slot >> 2);        // 128-row q-supertile, heavy first
  const int ntile = (qt + 1) * 2;
  const int t = threadIdx.x, lane = t & 63, wid = t >> 6;
  const int l31 = lane & 31, h = lane >> 5;
  const int h16 = h * 16, h4 = h * 4;
  const size_t base = (size_t)bh * (S_ * HD_);
  const int qrow0 = qt * 128 + wid * 32;
  const float NEG = -1e30f;
  const float SCALE = 0.18033688011112042f;  // (1/8)*log2(e)
  const int srow = lane >> 3;
  const int scol = ((lane & 7) ^ srow) << 3;

  bf16x8 qf[4];
  {
    const unsigned short* qp = Qb + base + (size_t)(qrow0 + l31) * HD_ + h * 8;
#pragma unroll
    for (int ks = 0; ks < 4; ++ks)
      qf[ks] = *reinterpret_cast<const bf16x8*>(qp + ks * 16);
  }
  f32x16 o[2] = {};
  float mrow = NEG, lrow = 0.f;

#define STAGE(buf, kvb0)                                                            \
  do {                                                                              \
    _Pragma("unroll") for (int c = 0; c < 2; ++c) {                                 \
      const int r8 = wid * 16 + c * 8;                                              \
      gll16(Kb + base + (size_t)((kvb0) + r8 + srow) * HD_ + scol, &Kl[buf][r8 * 64]); \
      gll16(Vt + base + (size_t)(r8 + srow) * S_ + (kvb0) + scol, &Vl[buf][r8 * 64]);  \
    }                                                                               \
  } while (0)

  STAGE(0, 0);
  __syncthreads();

  for (int kt = 0; kt < ntile; ++kt) {
    const int cur = kt & 1;
    const int kv0 = kt * 64;
    if (kt + 1 < ntile) STAGE(cur ^ 1, kv0 + 64);
    if (kv0 <= qrow0 + 31) {  // wave-uniform: skip fully-masked tiles
      // ---- QK^T (swapped): C col = q = l31 per lane
      f32x16 s0 = {}, s1 = {};
      {
        const char* kb0 = (const char*)&Kl[cur][0] + l31 * 128;
        const char* kb1 = kb0 + 32 * 128;
        const int key = (l31 & 7) << 4;
#pragma unroll
        for (int ks = 0; ks < 4; ++ks) {
          bf16x8 ka = *(const bf16x8*)(kb0 + ((ks * 32 + h16) ^ key));
          s0 = MFMA32(ka, qf[ks], s0);
        }
#pragma unroll
        for (int ks = 0; ks < 4; ++ks) {
          bf16x8 ka = *(const bf16x8*)(kb1 + ((ks * 32 + h16) ^ key));
          s1 = MFMA32(ka, qf[ks], s1);
        }
      }
      // ---- scale (+ mask on diagonal tiles)
      if (kv0 + 63 > qrow0) {
        const int lim0 = qrow0 + l31 - kv0;
        const int lim1 = lim0 - 32;
#pragma unroll
        for (int r = 0; r < 16; ++r) {
          const int cr = (r & 3) + 8 * (r >> 2);
          s0[r] = (cr + h4 > lim0) ? NEG : s0[r] * SCALE;
          s1[r] = (cr + h4 > lim1) ? NEG : s1[r] * SCALE;
        }
      } else {
#pragma unroll
        for (int r = 0; r < 16; ++r) { s0[r] *= SCALE; s1[r] *= SCALE; }
      }
      // ---- row max: in-lane tree + one cross-half swap
      float mx[8];
#pragma unroll
      for (int r = 0; r < 8; ++r)
        mx[r] = fmaxf(fmaxf(s0[r], s0[r + 8]), fmaxf(s1[r], s1[r + 8]));
#pragma unroll
      for (int st = 4; st > 0; st >>= 1)
#pragma unroll
        for (int r = 0; r < st; ++r) mx[r] = fmaxf(mx[r], mx[r + st]);
      const float pmax = fmaxf(mx[0], __shfl_xor(mx[0], 32));
      // ---- defer-rescale (THR=8, exp2 domain)
      if (!__all(pmax - mrow <= 8.f)) {
        const float mn = fmaxf(mrow, pmax);
        const float al = exp2f(mrow - mn);
        mrow = mn;
        lrow *= al;
#pragma unroll
        for (int r = 0; r < 16; ++r) { o[0][r] *= al; o[1][r] *= al; }
      }
      // ---- exp + row sum
#pragma unroll
      for (int r = 0; r < 16; ++r) {
        s0[r] = exp2f(s0[r] - mrow);
        s1[r] = exp2f(s1[r] - mrow);
      }
      float px[8];
#pragma unroll
      for (int r = 0; r < 8; ++r)
        px[r] = (s0[r] + s0[r + 8]) + (s1[r] + s1[r + 8]);
#pragma unroll
      for (int st = 4; st > 0; st >>= 1)
#pragma unroll
        for (int r = 0; r < st; ++r) px[r] += px[r + st];
      lrow += px[0] + __shfl_xor(px[0], 32);
      // ---- pack P -> bf16 B-operand fragments (cvt_pk + permlane32_swap)
      // pa[ks] slot i must hold P[q=l31][kv = ks*16 + h*8 + i].
      // (word0, word2) = plswap2(w0, w2); (word1, word3) = plswap2(w1, w3).
      bf16x8 pa[4];
      {
        union { unsigned u[4]; bf16x8 v; } uu;
        unsigned a0, a1, a2, a3, w0, w1, w2, w3;
        w0 = pk2(s0[0], s0[1]); w1 = pk2(s0[2], s0[3]);
        w2 = pk2(s0[4], s0[5]); w3 = pk2(s0[6], s0[7]);
        plswap2(a0, a2, w0, w2); plswap2(a1, a3, w1, w3);
        uu.u[0] = a0; uu.u[1] = a1; uu.u[2] = a2; uu.u[3] = a3; pa[0] = uu.v;
        w0 = pk2(s0[8], s0[9]); w1 = pk2(s0[10], s0[11]);
        w2 = pk2(s0[12], s0[13]); w3 = pk2(s0[14], s0[15]);
        plswap2(a0, a2, w0, w2); plswap2(a1, a3, w1, w3);
        uu.u[0] = a0; uu.u[1] = a1; uu.u[2] = a2; uu.u[3] = a3; pa[1] = uu.v;
        w0 = pk2(s1[0], s1[1]); w1 = pk2(s1[2], s1[3]);
        w2 = pk2(s1[4], s1[5]); w3 = pk2(s1[6], s1[7]);
        plswap2(a0, a2, w0, w2); plswap2(a1, a3, w1, w3);
        uu.u[0] = a0; uu.u[1] = a1; uu.u[2] = a2; uu.u[3] = a3; pa[2] = uu.v;
        w0 = pk2(s1[8], s1[9]); w1 = pk2(s1[10], s1[11]);
        w2 = pk2(s1[12], s1[13]); w3 = pk2(s1[14], s1[15]);
        plswap2(a0, a2, w0, w2); plswap2(a1, a3, w1, w3);
        uu.u[0] = a0; uu.u[1] = a1; uu.u[2] = a2; uu.u[3] = a3; pa[3] = uu.v;
      }
      // ---- PV: O^T = V^T * P^T  (C col = q = l31 -> per-lane scalar rescale)
#pragma unroll
      for (int hb = 0; hb < 2; ++hb) {
        const char* vb = (const char*)&Vl[cur][0] + (hb * 32 + l31) * 128;
        const int key = (l31 & 7) << 4;
#pragma unroll
        for (int ks = 0; ks < 4; ++ks) {
          bf16x8 va = *(const bf16x8*)(vb + ((ks * 32 + h16) ^ key));
          o[hb] = MFMA32(va, pa[ks], o[hb]);
        }
      }
    }
    __syncthreads();
  }
  // ---- epilogue: O^T -> LDS (freed K/V buffers) -> coalesced bf16 stores
  float* ob = (float*)((wid & 2) ? &Vl[wid & 1][0] : &Kl[wid & 1][0]);
  const float rl = 1.0f / lrow;
#pragma unroll
  for (int hb = 0; hb < 2; ++hb)
#pragma unroll
    for (int r = 0; r < 16; ++r) {
      const int col = hb * 32 + (r & 3) + 8 * (r >> 2) + h4;
      ob[l31 * 64 + (col ^ ((l31 & 7) << 2))] = o[hb][r] * rl;
    }
  __asm__ volatile("s_waitcnt lgkmcnt(0)" ::: "memory");
#pragma unroll
  for (int p = 0; p < 8; ++p) {
    const int r = (lane >> 4) + p * 4;
    const int ce = ((lane & 15) * 4) ^ ((r & 7) << 2);
    const f32x4 v = *reinterpret_cast<const f32x4*>(&ob[r * 64 + ce]);
    u16x4 w = {f2bf(v[0]), f2bf(v[1]), f2bf(v[2]), f2bf(v[3])};
    *reinterpret_cast<u16x4*>(&Cxt[base + (size_t)(qrow0 + r) * HD_ + (lane & 15) * 4]) = w;
  }
}

// ---------------- Output projection: out[4096,1024] = Ctx @ WoT^T + bias (fp32 out)
// Ctx is head-blocked [b][h][s][hd]; K-step 64 = exactly one head plane.
__global__ __launch_bounds__(256) void gemm_out(
    const unsigned short* __restrict__ Cxt, const unsigned short* __restrict__ WT,
    const float* __restrict__ bias, float* __restrict__ out) {
  constexpr int NM = 1024;
  __shared__ __align__(16) unsigned short As[128][72];
  __shared__ __align__(16) unsigned short Bs[128][72];
  const int m0 = blockIdx.y * 128, n0 = blockIdx.x * 128;
  const int t = threadIdx.x;
  const int lane = t & 63, wid = t >> 6;
  const int wr = wid >> 1, wc = wid & 1;
  const int l15 = lane & 15, l16 = lane >> 4;
  f32x4 acc[4][4] = {};
  const int col8 = (t & 7) * 8, row8 = t >> 3;
  for (int k0 = 0; k0 < KDIM; k0 += 64) {
    const int head = k0 >> 6;
#pragma unroll
    for (int u = 0; u < 4; ++u) {
      const int row = row8 + u * 32;
      const int gr = m0 + row;
      const unsigned short* src =
          Cxt + ((((size_t)(gr >> 11) * H_ + head) << 11) + (gr & 2047)) * HD_ + col8;
      *reinterpret_cast<s16x8*>(&As[row][col8]) = *reinterpret_cast<const s16x8*>(src);
    }
#pragma unroll
    for (int u = 0; u < 4; ++u) {
      const int row = row8 + u * 32;
      *reinterpret_cast<s16x8*>(&Bs[row][col8]) =
          *reinterpret_cast<const s16x8*>(WT + (size_t)(n0 + row) * KDIM + k0 + col8);
    }
    __syncthreads();
#pragma unroll
    for (int ks = 0; ks < 2; ++ks) {
      bf16x8 af[4], bfr[4];
#pragma unroll
      for (int m = 0; m < 4; ++m)
        af[m] = *reinterpret_cast<const bf16x8*>(&As[wr * 64 + m * 16 + l15][ks * 32 + l16 * 8]);
#pragma unroll
      for (int n = 0; n < 4; ++n)
        bfr[n] = *reinterpret_cast<const bf16x8*>(&Bs[wc * 64 + n * 16 + l15][ks * 32 + l16 * 8]);
#pragma unroll
      for (int m = 0; m < 4; ++m)
#pragma unroll
        for (int n = 0; n < 4; ++n)
          acc[m][n] = MFMA16(af[m], bfr[n], acc[m][n]);
    }
    __syncthreads();
  }
#pragma unroll
  for (int n = 0; n < 4; ++n) {
    const int col = n0 + wc * 64 + n * 16 + l15;
    const float bv = bias[col];
#pragma unroll
    for (int m = 0; m < 4; ++m) {
#pragma unroll
      for (int j = 0; j < 4; ++j) {
        const int row = m0 + wr * 64 + m * 16 + l16 * 4 + j;
        out[(size_t)row * NM + col] = acc[m][n][j] + bv;
      }
    }
  }
}

extern "C" void kernel_launch(void* const* d_in, const int* in_sizes, int n_in,
                              void* d_out, int out_size, void* d_ws, size_t ws_size,
                              hipStream_t stream) {
  const float* x = (const float*)d_in[0];
  const float* w_qkv = (const float*)d_in[1];
  const float* b_qkv = (const float*)d_in[2];
  const float* w_out = (const float*)d_in[3];
  const float* b_out = (const float*)d_in[4];
  float* out = (float*)d_out;

  const size_t NTOK = (size_t)B_ * H_ * S_ * HD_;  // 4,194,304 elements
  unsigned short* Qb = (unsigned short*)d_ws;
  unsigned short* Kb = Qb + NTOK;
  unsigned short* Vt = Kb + NTOK;                  // V stored transposed [b,h,hd,s]
  unsigned short* WqT = Vt + NTOK;                 // [3072][1024]
  unsigned short* WoT = WqT + (size_t)3072 * 1024; // [1024][1024]
  unsigned short* Xbf = WoT + (size_t)1024 * 1024; // [4096][1024]
  unsigned short* Cxt = Xbf;                       // alias: Xbf dead before attn writes

  hipLaunchKernelGGL(x2bf, dim3(2048), dim3(256), 0, stream, x, Xbf);
  hipLaunchKernelGGL(transpose_w, dim3(48, 16), dim3(256), 0, stream, w_qkv, WqT, 3072);
  hipLaunchKernelGGL(transpose_w, dim3(16, 16), dim3(256), 0, stream, w_out, WoT, 1024);
  hipLaunchKernelGGL(gemm_qkv, dim3(24, 32), dim3(256), 0, stream, Xbf, WqT, b_qkv, Qb, Kb, Vt);
  hipLaunchKernelGGL(attn, dim3(512), dim3(256), 0, stream, Qb, Kb, Vt, Cxt);
  hipLaunchKernelGGL(gemm_out, dim3(8, 32), dim3(256), 0, stream, Cxt, WoT, b_out, out);
}